// Round 6
// baseline (659.330 us; speedup 1.0000x reference)
//
#include <hip/hip_runtime.h>
#include <hip/hip_bf16.h>

#define SQL  2048
#define SKVL 4096
#define DIML 1024

typedef __attribute__((ext_vector_type(8))) short short8;
typedef __attribute__((ext_vector_type(4))) float f32x4;

#define LOG2E 1.4426950408889634f
#define MBIGC (10000.0f * LOG2E)

__device__ __forceinline__ short f2s(float f) {
  return __builtin_bit_cast(short, __float2bfloat16(f));
}
__device__ __forceinline__ float s2f(short s) {
  return __bfloat162float(__builtin_bit_cast(__hip_bfloat16, s));
}

// swizzled LDS address for 128-byte-stride rows
__device__ __forceinline__ char* swz_addr(char* base, int row, int colByte) {
  return base + (row * 128 + (colByte ^ ((row & 7) << 4)));
}

// ---------------- x (f32) -> bf16 ----------------
__global__ __launch_bounds__(256) void convert_x_kernel(
    const float* __restrict__ x, short* __restrict__ xbf)
{
  const size_t i = ((size_t)blockIdx.x * 256 + threadIdx.x) * 8;
  float4 a = *(const float4*)&x[i];
  float4 b = *(const float4*)&x[i + 4];
  short8 o;
  o[0] = f2s(a.x); o[1] = f2s(a.y); o[2] = f2s(a.z); o[3] = f2s(a.w);
  o[4] = f2s(b.x); o[5] = f2s(b.y); o[6] = f2s(b.z); o[7] = f2s(b.w);
  *(short8*)&xbf[i] = o;
}

// ---------------- weight transpose+convert: WT[n][k] = bf16(W[k][n]) ----------------
__global__ __launch_bounds__(256) void transpose_w_kernel(
    const float* __restrict__ W0, const float* __restrict__ W1,
    const float* __restrict__ W2, const float* __restrict__ W3,
    short* __restrict__ WT)
{
  __shared__ float T[64][65];
  const int bid = blockIdx.x;
  const int w = bid >> 8;
  const float* W = (w == 0) ? W0 : (w == 1) ? W1 : (w == 2) ? W2 : W3;
  short* D = WT + (size_t)w * 1048576;
  const int tile = bid & 255;
  const int r0 = (tile >> 4) * 64;
  const int c0 = (tile & 15) * 64;
  const int t = threadIdx.x;
  const int row = t >> 2;
  const int q = t & 3;
#pragma unroll
  for (int i = 0; i < 4; i++)
    *(float4*)&T[row][q * 16 + i * 4] =
        *(const float4*)&W[(size_t)(r0 + row) * 1024 + c0 + q * 16 + i * 4];
  __syncthreads();
  short8 o0, o1;
#pragma unroll
  for (int j = 0; j < 8; j++) {
    o0[j] = f2s(T[q * 16 + j][row]);
    o1[j] = f2s(T[q * 16 + 8 + j][row]);
  }
  *(short8*)&D[(size_t)(c0 + row) * 1024 + r0 + q * 16] = o0;
  *(short8*)&D[(size_t)(c0 + row) * 1024 + r0 + q * 16 + 8] = o1;
}

// ---------------- copy caches into d_out (f32) + K cache rows into Kbf (bf16) ----------------
__global__ __launch_bounds__(256) void copy_cache_kernel(
    const float* __restrict__ kc, const float* __restrict__ vc,
    float* __restrict__ out, short* __restrict__ Kbf)
{
  const int idx = blockIdx.x * 256 + threadIdx.x;
  const int tensor = idx >> 19;
  const int cc = idx & 524287;
  const size_t e = (size_t)cc * 8;
  const int b = (int)(e >> 21);
  const size_t rem = e & 2097151;
  const float* src = tensor ? vc : kc;
  float* dst = out + (tensor ? 12582912u : 4194304u) + (size_t)b * 4194304u + rem;
  float4 a = *(const float4*)&src[e];
  float4 bb = *(const float4*)&src[e + 4];
  *(float4*)dst = a;
  *(float4*)(dst + 4) = bb;
  if (tensor == 0) {
    short8 o;
    o[0] = f2s(a.x); o[1] = f2s(a.y); o[2] = f2s(a.z); o[3] = f2s(a.w);
    o[4] = f2s(bb.x); o[5] = f2s(bb.y); o[6] = f2s(bb.z); o[7] = f2s(bb.w);
    *(short8*)&Kbf[(size_t)b * 4194304u + rem] = o;
  }
}

// ---------------- mask (f32 [B][SQ][SKV]) -> bit-packed maskW [B][32 qb][SKV] uint64 ----------------
__global__ __launch_bounds__(256) void pack_mask_kernel(
    const float* __restrict__ mask, unsigned long long* __restrict__ maskW)
{
  __shared__ float T[64][65];
  const int bid = blockIdx.x;          // b(2) x qt(32) x kt(64)
  const int ktile = bid & 63;
  const int qtile = (bid >> 6) & 31;
  const int b = bid >> 11;
  const int q0 = qtile * 64, k0 = ktile * 64;
  const int t = threadIdx.x;
  const int row = t >> 2;
  const int q4 = t & 3;
  const float* src = mask + (size_t)(b * SQL + q0 + row) * SKVL + k0 + q4 * 16;
#pragma unroll
  for (int i = 0; i < 4; i++)
    *(float4*)&T[row][q4 * 16 + i * 4] = *(const float4*)&src[i * 4];
  __syncthreads();
  const int wv = t >> 6, ln = t & 63;
#pragma unroll
  for (int j = 0; j < 16; j++) {
    const int kv = wv * 16 + j;
    unsigned long long w = __ballot(T[ln][kv] > 0.5f);
    if (ln == 0)
      maskW[((size_t)(b * 32 + qtile)) * SKVL + k0 + kv] = w;
  }
}

// ---------------- GEMM: C = A(bf16)[4096,1024] * BT^T + bias(f32) ----------------
__global__ __launch_bounds__(256) void gemm_bt_bias(
    const short* __restrict__ A,
    const short* __restrict__ BT,
    const float* __restrict__ bias,
    float* __restrict__ Cf,
    short* __restrict__ Cb,
    int dst_batch_rows, int dst_row0, float oscale)
{
  constexpr int K = 1024;
  __shared__ __align__(16) short As[128 * 32];
  __shared__ __align__(16) short Bs[128 * 32];
  const int tid = threadIdx.x;
  const int lane = tid & 63;
  const int wave = tid >> 6;
  const int bid = blockIdx.x;
  const int nb = bid & 7;
  const int mb = bid >> 3;
  const int wm = wave >> 1;
  const int wn = wave & 1;
  const int g = lane >> 4;
  const int fr = lane & 15;

  f32x4 acc[4][4] = {};

  const int c0 = tid, c1 = tid + 256;
  const short* Ab0 = A + (size_t)(mb * 128 + (c0 >> 2)) * K + (c0 & 3) * 8;
  const short* Ab1 = A + (size_t)(mb * 128 + (c1 >> 2)) * K + (c1 & 3) * 8;
  const short* Bb0 = BT + (size_t)(nb * 128 + (c0 >> 2)) * K + (c0 & 3) * 8;
  const short* Bb1 = BT + (size_t)(nb * 128 + (c1 >> 2)) * K + (c1 & 3) * 8;

  for (int k0 = 0; k0 < K; k0 += 32) {
    __syncthreads();
    *(short8*)&As[c0 * 8] = *(const short8*)&Ab0[k0];
    *(short8*)&As[c1 * 8] = *(const short8*)&Ab1[k0];
    *(short8*)&Bs[c0 * 8] = *(const short8*)&Bb0[k0];
    *(short8*)&Bs[c1 * 8] = *(const short8*)&Bb1[k0];
    __syncthreads();
    short8 af[4], bfv[4];
#pragma unroll
    for (int m = 0; m < 4; m++)
      af[m] = *(const short8*)&As[(wm * 64 + m * 16 + fr) * 32 + g * 8];
#pragma unroll
    for (int n = 0; n < 4; n++)
      bfv[n] = *(const short8*)&Bs[(wn * 64 + n * 16 + fr) * 32 + g * 8];
#pragma unroll
    for (int m = 0; m < 4; m++)
#pragma unroll
      for (int n = 0; n < 4; n++)
        acc[m][n] = __builtin_amdgcn_mfma_f32_16x16x32_bf16(af[m], bfv[n], acc[m][n], 0, 0, 0);
  }

  const int gm = mb * 128 + wm * 64;
  const int gn = nb * 128 + wn * 64;
  float bv[4];
#pragma unroll
  for (int n = 0; n < 4; n++) bv[n] = bias[gn + n * 16 + fr];
#pragma unroll
  for (int m = 0; m < 4; m++) {
#pragma unroll
    for (int r = 0; r < 4; r++) {
      const int row = gm + m * 16 + g * 4 + r;
      const int drow = (row >> 11) * dst_batch_rows + dst_row0 + (row & 2047);
      float vals[4];
#pragma unroll
      for (int n = 0; n < 4; n++) vals[n] = (acc[m][n][r] + bv[n]) * oscale;
      if (Cf) {
#pragma unroll
        for (int n = 0; n < 4; n++)
          Cf[(size_t)drow * 1024 + gn + n * 16 + fr] = vals[n];
      }
      if (Cb) {
#pragma unroll
        for (int n = 0; n < 4; n++)
          Cb[(size_t)drow * 1024 + gn + n * 16 + fr] = f2s(vals[n]);
      }
    }
  }
}

// ---------------- V (f32, d_out region) -> VT bf16 [B*H][64][SKVL] ----------------
__global__ __launch_bounds__(256) void transpose_v_kernel(
    const float* __restrict__ Vf, short* __restrict__ VT)
{
  __shared__ float T[64][65];
  const int bid = blockIdx.x;      // b(2) x h(16) x kb(64)
  const int kb = bid & 63;
  const int h = (bid >> 6) & 15;
  const int b = bid >> 10;
  const int kt = kb * 64;
  const int t = threadIdx.x;
  const int row = t >> 2;
  const int q = t & 3;
  const float* src = Vf + (size_t)(b * SKVL + kt + row) * DIML + h * 64 + q * 16;
#pragma unroll
  for (int i = 0; i < 4; i++)
    *(float4*)&T[row][q * 16 + i * 4] = *(const float4*)&src[i * 4];
  __syncthreads();
  short8 o0, o1;
#pragma unroll
  for (int j = 0; j < 8; j++) {
    o0[j] = f2s(T[q * 16 + j][row]);
    o1[j] = f2s(T[q * 16 + 8 + j][row]);
  }
  short* D = VT + (size_t)((b * 16 + h) * 64 + row) * SKVL + kt;
  *(short8*)&D[q * 16] = o0;
  *(short8*)&D[q * 16 + 8] = o1;
}

// One pipelined sub-iteration: QK(KRC) | prefetch K[KTN]->KRN | early V[KT] |
// mask | defer-max softmax | pack P | PV(vr).
#define ATTN_STEP(KT, KRC, KRN, KTN)                                          \
  do {                                                                        \
    f32x4 s[4] = {};                                                          \
    _Pragma("unroll")                                                         \
    for (int n = 0; n < 4; n++) {                                             \
      s[n] = __builtin_amdgcn_mfma_f32_16x16x32_bf16(qf[0], KRC[n * 2], s[n], 0, 0, 0);     \
      s[n] = __builtin_amdgcn_mfma_f32_16x16x32_bf16(qf[1], KRC[n * 2 + 1], s[n], 0, 0, 0); \
    }                                                                         \
    _Pragma("unroll")                                                         \
    for (int n = 0; n < 4; n++) {                                             \
      const short* kp_ = Kp + (size_t)((KTN) + n * 16 + c) * DIML + g * 8;    \
      KRN[n * 2]     = *(const short8*)kp_;                                   \
      KRN[n * 2 + 1] = *(const short8*)(kp_ + 32);                            \
    }                                                                         \
    _Pragma("unroll")                                                         \
    for (int n = 0; n < 4; n++) {                                             \
      _Pragma("unroll")                                                       \
      for (int ks = 0; ks < 2; ks++)                                          \
        vr[n * 2 + ks] =                                                      \
            *(const short8*)&Vp[(size_t)(n * 16 + c) * SKVL + (KT) + ks * 32 + g * 8]; \
    }                                                                         \
    _Pragma("unroll")                                                         \
    for (int n = 0; n < 4; n++) {                                             \
      const unsigned bits_ = (unsigned)(Mw[(KT) + n * 16 + c] >> mshift) & 0xFu; \
      _Pragma("unroll")                                                       \
      for (int r = 0; r < 4; r++)                                             \
        s[n][r] = fmaf((float)((bits_ >> r) & 1u), -MBIGC, s[n][r]);          \
    }                                                                         \
    float mloc[4];                                                            \
    _Pragma("unroll")                                                         \
    for (int r = 0; r < 4; r++)                                               \
      mloc[r] = fmaxf(fmaxf(s[0][r], s[1][r]), fmaxf(s[2][r], s[3][r]));      \
    const int grow_ =                                                         \
        (mloc[0] > m_run[0] + 11.5f) || (mloc[1] > m_run[1] + 11.5f) ||       \
        (mloc[2] > m_run[2] + 11.5f) || (mloc[3] > m_run[3] + 11.5f);         \
    if (__any(grow_)) {                                                       \
      _Pragma("unroll")                                                       \
      for (int r = 0; r < 4; r++) {                                           \
        float mt = mloc[r];                                                   \
        _Pragma("unroll")                                                     \
        for (int off = 1; off < 16; off <<= 1) mt = fmaxf(mt, __shfl_xor(mt, off)); \
        const float mnew = fmaxf(m_run[r], mt);                               \
        const float sc = exp2f(m_run[r] - mnew);                              \
        m_run[r] = mnew;                                                      \
        lpart[r] *= sc;                                                       \
        ctxa[0][r] *= sc; ctxa[1][r] *= sc; ctxa[2][r] *= sc; ctxa[3][r] *= sc; \
      }                                                                       \
    }                                                                         \
    _Pragma("unroll")                                                         \
    for (int r = 0; r < 4; r++) {                                             \
      _Pragma("unroll")                                                       \
      for (int n = 0; n < 4; n++) {                                           \
        float p_ = exp2f(s[n][r] - m_run[r]);                                 \
        lpart[r] += p_;                                                       \
        *(short*)swz_addr(PlW, g * 4 + r, (n * 16 + c) * 2) = f2s(p_);        \
      }                                                                       \
    }                                                                         \
    _Pragma("unroll")                                                         \
    for (int ks = 0; ks < 2; ks++) {                                          \
      short8 pa_ = *(short8*)swz_addr(PlW, c, ks * 64 + g * 16);              \
      _Pragma("unroll")                                                       \
      for (int n = 0; n < 4; n++)                                             \
        ctxa[n] = __builtin_amdgcn_mfma_f32_16x16x32_bf16(pa_, vr[n * 2 + ks], ctxa[n], 0, 0, 0); \
    }                                                                         \
  } while (0)

// ---------------- flash attention, KV-split x2, XCD swizzle, SW-pipelined ----------------
__global__ __launch_bounds__(256) void attn_kernel(
    const short* __restrict__ Q,
    const short* __restrict__ Kb_,
    const short* __restrict__ VT_,
    const unsigned long long* __restrict__ maskW,
    short* __restrict__ pctx,
    float2* __restrict__ ml)
{
  __shared__ __align__(16) char Pl[4][16 * 128];
  const int tid = threadIdx.x;
  const int lane = tid & 63;
  const int wave = tid >> 6;
  const int gid = blockIdx.x;          // 0..2047
  const int xcd = gid & 7;
  const int seq = gid >> 3;            // 0..255
  const int group = xcd * 8 + (seq >> 5);  // 0..63
  const int qb = seq & 31;
  const int half = group & 1;
  const int bh = group >> 1;
  const int b = bh >> 4;
  const int h = bh & 15;
  const int q0 = qb * 64 + wave * 16;
  const int g = lane >> 4;
  const int c = lane & 15;
  char* PlW = Pl[wave];

  short8 qf[2];
  {
    const short* qp = Q + (size_t)(b * SQL + q0 + c) * DIML + h * 64 + g * 8;
    qf[0] = *(const short8*)qp;
    qf[1] = *(const short8*)(qp + 32);
  }

  float m_run[4] = {-1e30f, -1e30f, -1e30f, -1e30f};
  float lpart[4] = {0.f, 0.f, 0.f, 0.f};
  f32x4 ctxa[4] = {};

  const short* Kp = Kb_ + (size_t)b * SKVL * DIML + h * 64;
  const short* Vp = VT_ + (size_t)(b * 16 + h) * 64 * SKVL;
  const unsigned long long* Mw = maskW + (size_t)(b * 32 + qb) * SKVL;
  const int mshift = wave * 16 + g * 4;

  const int k_beg = half * (SKVL / 2);
  const int k_end = k_beg + SKVL / 2;

  short8 krA[8], krB[8], vr[8];
#pragma unroll
  for (int n = 0; n < 4; n++) {
    const short* kp_ = Kp + (size_t)(k_beg + n * 16 + c) * DIML + g * 8;
    krA[n * 2]     = *(const short8*)kp_;
    krA[n * 2 + 1] = *(const short8*)(kp_ + 32);
  }

  for (int kt = k_beg; kt < k_end; kt += 128) {
    ATTN_STEP(kt,      krA, krB, kt + 64);
    ATTN_STEP(kt + 64, krB, krA, kt + 128);  // last prefetch overreads into ws scratch (never consumed)
  }

  // epilogue: reduce l across the 16-lane group, store partials
#pragma unroll
  for (int r = 0; r < 4; r++) {
    float l = lpart[r];
#pragma unroll
    for (int off = 1; off < 16; off <<= 1) l += __shfl_xor(l, off);
    const int rg = ((b * 16 + h) << 11) + q0 + g * 4 + r;
    const size_t base = ((size_t)half << 22) + (size_t)rg * 64;
#pragma unroll
    for (int n = 0; n < 4; n++)
      pctx[base + n * 16 + c] = f2s(ctxa[n][r]);
    if (c == 0) ml[half * 65536 + rg] = make_float2(m_run[r], l);
  }
}

// ---------------- combine two KV-halves -> ctx bf16 [B*SQ][DIM] ----------------
__global__ __launch_bounds__(256) void combine_kernel(
    const short* __restrict__ pctx, const float2* __restrict__ ml,
    short* __restrict__ ctxb)
{
  const int t = blockIdx.x * 256 + threadIdx.x;   // 262144
  const int r = t >> 2;
  const int seg = (t & 3) * 16;
  const float2 ml0 = ml[r];
  const float2 ml1 = ml[65536 + r];
  const float m = fmaxf(ml0.x, ml1.x);
  const float w0 = exp2f(ml0.x - m);
  const float w1 = exp2f(ml1.x - m);
  const float inv = 1.0f / (ml0.y * w0 + ml1.y * w1);
  const short8 a0 = *(const short8*)&pctx[(size_t)r * 64 + seg];
  const short8 a1 = *(const short8*)&pctx[(size_t)r * 64 + seg + 8];
  const short8 b0 = *(const short8*)&pctx[(1ull << 22) + (size_t)r * 64 + seg];
  const short8 b1 = *(const short8*)&pctx[(1ull << 22) + (size_t)r * 64 + seg + 8];
  short8 o0, o1;
#pragma unroll
  for (int j = 0; j < 8; j++) {
    o0[j] = f2s((s2f(a0[j]) * w0 + s2f(b0[j]) * w1) * inv);
    o1[j] = f2s((s2f(a1[j]) * w0 + s2f(b1[j]) * w1) * inv);
  }
  const int b = r >> 15;
  const int h = (r >> 11) & 15;
  const int q = r & 2047;
  short* D = ctxb + (size_t)(b * 2048 + q) * 1024 + h * 64 + seg;
  *(short8*)&D[0] = o0;
  *(short8*)&D[8] = o1;
}

extern "C" void kernel_launch(void* const* d_in, const int* in_sizes, int n_in,
                              void* d_out, int out_size, void* d_ws, size_t ws_size,
                              hipStream_t stream)
{
  const float* x   = (const float*)d_in[0];
  const float* kc  = (const float*)d_in[1];
  const float* vc  = (const float*)d_in[2];
  const float* msk = (const float*)d_in[3];
  const float* Wq  = (const float*)d_in[4];
  const float* bq  = (const float*)d_in[5];
  const float* Wk  = (const float*)d_in[6];
  const float* bk  = (const float*)d_in[7];
  const float* Wv  = (const float*)d_in[8];
  const float* bv  = (const float*)d_in[9];
  const float* Wo  = (const float*)d_in[10];
  const float* bo  = (const float*)d_in[11];

  float* outf = (float*)d_out;
  float* kout = outf + 4194304;
  float* vout = outf + 12582912;

  short* ws_s  = (short*)d_ws;
  short* WT    = ws_s;                            // 8 MB
  short* xbf   = ws_s + (size_t)4 * 1048576;      // 8 MB (reused as ctx)
  short* qbf   = ws_s + (size_t)8 * 1048576;      // 8 MB
  short* Kbf   = ws_s + (size_t)12 * 1048576;     // 16 MB
  short* VTb   = ws_s + (size_t)20 * 1048576;     // 16 MB
  unsigned long long* maskW = (unsigned long long*)(ws_s + (size_t)28 * 1048576);  // 2 MB
  short* pctx  = ws_s + (size_t)44 * 1048576;     // 16 MB
  float2* mlp  = (float2*)(ws_s + (size_t)52 * 1048576);  // 1 MB
  short* ctxb  = xbf;

  const float qscale = 0.125f * LOG2E;

  convert_x_kernel<<<2048, 256, 0, stream>>>(x, xbf);
  transpose_w_kernel<<<1024, 256, 0, stream>>>(Wq, Wk, Wv, Wo, WT);
  copy_cache_kernel<<<4096, 256, 0, stream>>>(kc, vc, outf, Kbf);
  pack_mask_kernel<<<4096, 256, 0, stream>>>(msk, maskW);
  gemm_bt_bias<<<256, 256, 0, stream>>>(xbf, WT,               bq, nullptr, qbf, 2048, 0, qscale);
  gemm_bt_bias<<<256, 256, 0, stream>>>(xbf, WT + 1048576,     bk, kout, Kbf,   4096, 2048, 1.0f);
  gemm_bt_bias<<<256, 256, 0, stream>>>(xbf, WT + 2 * 1048576, bv, vout, nullptr, 4096, 2048, 1.0f);
  transpose_v_kernel<<<2048, 256, 0, stream>>>(vout, VTb);
  attn_kernel<<<2048, 256, 0, stream>>>(qbf, Kbf, VTb, maskW, pctx, mlp);
  combine_kernel<<<1024, 256, 0, stream>>>(pctx, mlp, ctxb);
  gemm_bt_bias<<<256, 256, 0, stream>>>(ctxb, WT + 3 * 1048576, bo, outf, nullptr, 2048, 0, 1.0f);
}

// Round 7
// 360.481 us; speedup vs baseline: 1.8290x; 1.8290x over previous
//
#include <hip/hip_runtime.h>
#include <hip/hip_bf16.h>

#define SQL  2048
#define SKVL 4096
#define DIML 1024

typedef __attribute__((ext_vector_type(8))) short short8;
typedef __attribute__((ext_vector_type(4))) float f32x4;

#define LOG2E 1.4426950408889634f
#define MBIGC (10000.0f * LOG2E)

__device__ __forceinline__ short f2s(float f) {
  return __builtin_bit_cast(short, __float2bfloat16(f));
}
__device__ __forceinline__ float s2f(short s) {
  return __bfloat162float(__builtin_bit_cast(__hip_bfloat16, s));
}

// swizzled LDS address for 128-byte-stride rows (XOR bits 4-6 with row&7)
__device__ __forceinline__ const char* swz_addr(const char* base, int row, int colByte) {
  return base + (row * 128 + (colByte ^ ((row & 7) << 4)));
}
__device__ __forceinline__ char* swz_addr(char* base, int row, int colByte) {
  return base + (row * 128 + (colByte ^ ((row & 7) << 4)));
}

// ---------------- x (f32) -> bf16 ----------------
__global__ __launch_bounds__(256) void convert_x_kernel(
    const float* __restrict__ x, short* __restrict__ xbf)
{
  const size_t i = ((size_t)blockIdx.x * 256 + threadIdx.x) * 8;
  float4 a = *(const float4*)&x[i];
  float4 b = *(const float4*)&x[i + 4];
  short8 o;
  o[0] = f2s(a.x); o[1] = f2s(a.y); o[2] = f2s(a.z); o[3] = f2s(a.w);
  o[4] = f2s(b.x); o[5] = f2s(b.y); o[6] = f2s(b.z); o[7] = f2s(b.w);
  *(short8*)&xbf[i] = o;
}

// ---------------- weight transpose+convert: WT[n][k] = bf16(W[k][n]) ----------------
__global__ __launch_bounds__(256) void transpose_w_kernel(
    const float* __restrict__ W0, const float* __restrict__ W1,
    const float* __restrict__ W2, const float* __restrict__ W3,
    short* __restrict__ WT)
{
  __shared__ float T[64][65];
  const int bid = blockIdx.x;
  const int w = bid >> 8;
  const float* W = (w == 0) ? W0 : (w == 1) ? W1 : (w == 2) ? W2 : W3;
  short* D = WT + (size_t)w * 1048576;
  const int tile = bid & 255;
  const int r0 = (tile >> 4) * 64;
  const int c0 = (tile & 15) * 64;
  const int t = threadIdx.x;
  const int row = t >> 2;
  const int q = t & 3;
#pragma unroll
  for (int i = 0; i < 4; i++)
    *(float4*)&T[row][q * 16 + i * 4] =
        *(const float4*)&W[(size_t)(r0 + row) * 1024 + c0 + q * 16 + i * 4];
  __syncthreads();
  short8 o0, o1;
#pragma unroll
  for (int j = 0; j < 8; j++) {
    o0[j] = f2s(T[q * 16 + j][row]);
    o1[j] = f2s(T[q * 16 + 8 + j][row]);
  }
  *(short8*)&D[(size_t)(c0 + row) * 1024 + r0 + q * 16] = o0;
  *(short8*)&D[(size_t)(c0 + row) * 1024 + r0 + q * 16 + 8] = o1;
}

// ---------------- copy caches into d_out (f32) + K cache rows into Kbf (bf16) ----------------
__global__ __launch_bounds__(256) void copy_cache_kernel(
    const float* __restrict__ kc, const float* __restrict__ vc,
    float* __restrict__ out, short* __restrict__ Kbf)
{
  const int idx = blockIdx.x * 256 + threadIdx.x;
  const int tensor = idx >> 19;
  const int cc = idx & 524287;
  const size_t e = (size_t)cc * 8;
  const int b = (int)(e >> 21);
  const size_t rem = e & 2097151;
  const float* src = tensor ? vc : kc;
  float* dst = out + (tensor ? 12582912u : 4194304u) + (size_t)b * 4194304u + rem;
  float4 a = *(const float4*)&src[e];
  float4 bb = *(const float4*)&src[e + 4];
  *(float4*)dst = a;
  *(float4*)(dst + 4) = bb;
  if (tensor == 0) {
    short8 o;
    o[0] = f2s(a.x); o[1] = f2s(a.y); o[2] = f2s(a.z); o[3] = f2s(a.w);
    o[4] = f2s(bb.x); o[5] = f2s(bb.y); o[6] = f2s(bb.z); o[7] = f2s(bb.w);
    *(short8*)&Kbf[(size_t)b * 4194304u + rem] = o;
  }
}

// ---------------- mask (f32 [B][SQ][SKV]) -> bit-packed maskW [B][32 qw][SKV] uint64 ----------------
__global__ __launch_bounds__(256) void pack_mask_kernel(
    const float* __restrict__ mask, unsigned long long* __restrict__ maskW)
{
  __shared__ float T[64][65];
  const int bid = blockIdx.x;          // b(2) x qt(32) x kt(64)
  const int ktile = bid & 63;
  const int qtile = (bid >> 6) & 31;
  const int b = bid >> 11;
  const int q0 = qtile * 64, k0 = ktile * 64;
  const int t = threadIdx.x;
  const int row = t >> 2;
  const int q4 = t & 3;
  const float* src = mask + (size_t)(b * SQL + q0 + row) * SKVL + k0 + q4 * 16;
#pragma unroll
  for (int i = 0; i < 4; i++)
    *(float4*)&T[row][q4 * 16 + i * 4] = *(const float4*)&src[i * 4];
  __syncthreads();
  const int wv = t >> 6, ln = t & 63;
#pragma unroll
  for (int j = 0; j < 16; j++) {
    const int kv = wv * 16 + j;
    unsigned long long w = __ballot(T[ln][kv] > 0.5f);
    if (ln == 0)
      maskW[((size_t)(b * 32 + qtile)) * SKVL + k0 + kv] = w;
  }
}

// ---------------- GEMM: C = A(bf16)[4096,1024] * BT^T + bias(f32) ----------------
__global__ __launch_bounds__(256) void gemm_bt_bias(
    const short* __restrict__ A,
    const short* __restrict__ BT,
    const float* __restrict__ bias,
    float* __restrict__ Cf,
    short* __restrict__ Cb,
    int dst_batch_rows, int dst_row0, float oscale)
{
  constexpr int K = 1024;
  __shared__ __align__(16) short As[128 * 32];
  __shared__ __align__(16) short Bs[128 * 32];
  const int tid = threadIdx.x;
  const int lane = tid & 63;
  const int wave = tid >> 6;
  const int bid = blockIdx.x;
  const int nb = bid & 7;
  const int mb = bid >> 3;
  const int wm = wave >> 1;
  const int wn = wave & 1;
  const int g = lane >> 4;
  const int fr = lane & 15;

  f32x4 acc[4][4] = {};

  const int c0 = tid, c1 = tid + 256;
  const short* Ab0 = A + (size_t)(mb * 128 + (c0 >> 2)) * K + (c0 & 3) * 8;
  const short* Ab1 = A + (size_t)(mb * 128 + (c1 >> 2)) * K + (c1 & 3) * 8;
  const short* Bb0 = BT + (size_t)(nb * 128 + (c0 >> 2)) * K + (c0 & 3) * 8;
  const short* Bb1 = BT + (size_t)(nb * 128 + (c1 >> 2)) * K + (c1 & 3) * 8;

  for (int k0 = 0; k0 < K; k0 += 32) {
    __syncthreads();
    *(short8*)&As[c0 * 8] = *(const short8*)&Ab0[k0];
    *(short8*)&As[c1 * 8] = *(const short8*)&Ab1[k0];
    *(short8*)&Bs[c0 * 8] = *(const short8*)&Bb0[k0];
    *(short8*)&Bs[c1 * 8] = *(const short8*)&Bb1[k0];
    __syncthreads();
    short8 af[4], bfv[4];
#pragma unroll
    for (int m = 0; m < 4; m++)
      af[m] = *(const short8*)&As[(wm * 64 + m * 16 + fr) * 32 + g * 8];
#pragma unroll
    for (int n = 0; n < 4; n++)
      bfv[n] = *(const short8*)&Bs[(wn * 64 + n * 16 + fr) * 32 + g * 8];
#pragma unroll
    for (int m = 0; m < 4; m++)
#pragma unroll
      for (int n = 0; n < 4; n++)
        acc[m][n] = __builtin_amdgcn_mfma_f32_16x16x32_bf16(af[m], bfv[n], acc[m][n], 0, 0, 0);
  }

  const int gm = mb * 128 + wm * 64;
  const int gn = nb * 128 + wn * 64;
  float bv[4];
#pragma unroll
  for (int n = 0; n < 4; n++) bv[n] = bias[gn + n * 16 + fr];
#pragma unroll
  for (int m = 0; m < 4; m++) {
#pragma unroll
    for (int r = 0; r < 4; r++) {
      const int row = gm + m * 16 + g * 4 + r;
      const int drow = (row >> 11) * dst_batch_rows + dst_row0 + (row & 2047);
      float vals[4];
#pragma unroll
      for (int n = 0; n < 4; n++) vals[n] = (acc[m][n][r] + bv[n]) * oscale;
      if (Cf) {
#pragma unroll
        for (int n = 0; n < 4; n++)
          Cf[(size_t)drow * 1024 + gn + n * 16 + fr] = vals[n];
      }
      if (Cb) {
#pragma unroll
        for (int n = 0; n < 4; n++)
          Cb[(size_t)drow * 1024 + gn + n * 16 + fr] = f2s(vals[n]);
      }
    }
  }
}

// ---------------- V (f32, d_out region) -> VT bf16 [B*H][64][SKVL] ----------------
__global__ __launch_bounds__(256) void transpose_v_kernel(
    const float* __restrict__ Vf, short* __restrict__ VT)
{
  __shared__ float T[64][65];
  const int bid = blockIdx.x;      // b(2) x h(16) x kb(64)
  const int kb = bid & 63;
  const int h = (bid >> 6) & 15;
  const int b = bid >> 10;
  const int kt = kb * 64;
  const int t = threadIdx.x;
  const int row = t >> 2;
  const int q = t & 3;
  const float* src = Vf + (size_t)(b * SKVL + kt + row) * DIML + h * 64 + q * 16;
#pragma unroll
  for (int i = 0; i < 4; i++)
    *(float4*)&T[row][q * 16 + i * 4] = *(const float4*)&src[i * 4];
  __syncthreads();
  short8 o0, o1;
#pragma unroll
  for (int j = 0; j < 8; j++) {
    o0[j] = f2s(T[q * 16 + j][row]);
    o1[j] = f2s(T[q * 16 + 8 + j][row]);
  }
  short* D = VT + (size_t)((b * 16 + h) * 64 + row) * SKVL + kt;
  *(short8*)&D[q * 16] = o0;
  *(short8*)&D[q * 16 + 8] = o1;
}

// ---------------- flash attention v7: LDS-staged K/V (global_load_lds, dbuf), ----------------
// 4 waves x 32 q-rows, KVBLK=64, KV-split x2, XCD-partitioned.
// Q bf16 (pre-scaled by 0.125*log2e); K bf16 [B][SKVL][DIML]; VT bf16 [B*H][64][SKVL];
// maskW bit-packed. Outputs unnormalized partial ctx (bf16) + (m,l) per row.
__global__ __launch_bounds__(256) void attn_kernel(
    const short* __restrict__ Q,
    const short* __restrict__ Kb_,
    const short* __restrict__ VT_,
    const unsigned long long* __restrict__ maskW,
    short* __restrict__ pctx,
    float2* __restrict__ ml)
{
  __shared__ __align__(16) char Kl[2][8192];   // [buf][64 kv][128B d], swizzled
  __shared__ __align__(16) char Vl[2][8192];   // [buf][64 d][128B kv], swizzled
  __shared__ __align__(16) char Pl[4][4096];   // [wave][32 q][128B kv], swizzled
  const int tid = threadIdx.x;
  const int lane = tid & 63;
  const int wave = tid >> 6;
  // XCD-partitioned bijective swizzle (1024 blocks, 8 XCDs)
  const int gid = blockIdx.x;
  const int xcd = gid & 7;
  const int seq = gid >> 3;                 // 0..127
  const int group = xcd * 8 + (seq >> 4);   // 0..63  (bh, half)
  const int qbB = seq & 15;                 // 0..15  (128-row q block)
  const int half = group & 1;
  const int bh = group >> 1;
  const int b = bh >> 4;
  const int h = bh & 15;
  const int g = lane >> 4;
  const int c = lane & 15;
  char* PlW = Pl[wave];

  const int qbase = qbB * 128 + wave * 32;

  // Q fragments: 2 m-subtiles x 2 k-chunks
  short8 qf[2][2];
#pragma unroll
  for (int m = 0; m < 2; m++) {
    const short* qp = Q + (size_t)(b * SQL + qbase + m * 16 + c) * DIML + h * 64 + g * 8;
    qf[m][0] = *(const short8*)qp;
    qf[m][1] = *(const short8*)(qp + 32);
  }

  float m_run[2][4], lpart[2][4];
#pragma unroll
  for (int m = 0; m < 2; m++)
#pragma unroll
    for (int r = 0; r < 4; r++) { m_run[m][r] = -1e30f; lpart[m][r] = 0.f; }
  f32x4 ctx[2][4] = {};

  const short* Kp = Kb_ + (size_t)b * SKVL * DIML + h * 64;
  const short* Vp = VT_ + (size_t)(b * 16 + h) * 64 * SKVL;
  const unsigned long long* Mw = maskW + (size_t)(b * 32 + qbB * 2 + (wave >> 1)) * SKVL;
  const int sh0 = (wave & 1) * 32 + g * 4;    // m=0 shift; m=1 adds 16

  // staging lane decomposition (pre-swizzled global source)
  const int srow = lane >> 3;                       // 0..7
  const int scol = ((lane & 7) ^ srow) * 8;         // shorts

  const int k_beg = half * (SKVL / 2);
  const int k_end = k_beg + SKVL / 2;

#define STAGE(BF, KT)                                                          \
  do {                                                                         \
    _Pragma("unroll")                                                          \
    for (int i = 0; i < 2; i++) {                                              \
      const short* gk = Kp + (size_t)((KT) + wave * 16 + i * 8 + srow) * DIML + scol; \
      __builtin_amdgcn_global_load_lds(                                        \
          (const __attribute__((address_space(1))) int*)gk,                    \
          (__attribute__((address_space(3))) int*)&Kl[BF][(wave * 16 + i * 8) * 128], \
          16, 0, 0);                                                           \
      const short* gv = Vp + (size_t)(wave * 16 + i * 8 + srow) * SKVL + (KT) + scol; \
      __builtin_amdgcn_global_load_lds(                                        \
          (const __attribute__((address_space(1))) int*)gv,                    \
          (__attribute__((address_space(3))) int*)&Vl[BF][(wave * 16 + i * 8) * 128], \
          16, 0, 0);                                                           \
    }                                                                          \
  } while (0)

  STAGE(0, k_beg);
  __syncthreads();

  for (int t = 0; t < (SKVL / 2) / 64; t++) {
    const int kt = k_beg + t * 64;
    const int cur = t & 1;
    // prefetch next tile into the other buffer (overread at end is harmless)
    STAGE(cur ^ 1, kt + 64);

    // mask words (tiny, L2-resident)
    unsigned long long mw[4];
#pragma unroll
    for (int n = 0; n < 4; n++) mw[n] = Mw[kt + n * 16 + c];

    // QK^T from LDS
    f32x4 s[2][4] = {};
#pragma unroll
    for (int n = 0; n < 4; n++) {
      short8 kf0 = *(const short8*)swz_addr(Kl[cur], n * 16 + c, g * 16);
      short8 kf1 = *(const short8*)swz_addr(Kl[cur], n * 16 + c, 64 + g * 16);
#pragma unroll
      for (int m = 0; m < 2; m++) {
        s[m][n] = __builtin_amdgcn_mfma_f32_16x16x32_bf16(qf[m][0], kf0, s[m][n], 0, 0, 0);
        s[m][n] = __builtin_amdgcn_mfma_f32_16x16x32_bf16(qf[m][1], kf1, s[m][n], 0, 0, 0);
      }
    }
    // additive mask from bits
#pragma unroll
    for (int n = 0; n < 4; n++) {
      const unsigned bits0 = (unsigned)(mw[n] >> sh0) & 0xFu;
      const unsigned bits1 = (unsigned)(mw[n] >> (sh0 + 16)) & 0xFu;
#pragma unroll
      for (int r = 0; r < 4; r++) {
        s[0][n][r] = fmaf((float)((bits0 >> r) & 1u), -MBIGC, s[0][n][r]);
        s[1][n][r] = fmaf((float)((bits1 >> r) & 1u), -MBIGC, s[1][n][r]);
      }
    }
    // defer-max online softmax (log2 domain)
    float mloc[2][4];
    int grow = 0;
#pragma unroll
    for (int m = 0; m < 2; m++)
#pragma unroll
      for (int r = 0; r < 4; r++) {
        mloc[m][r] = fmaxf(fmaxf(s[m][0][r], s[m][1][r]), fmaxf(s[m][2][r], s[m][3][r]));
        grow |= (mloc[m][r] > m_run[m][r] + 11.5f);
      }
    if (__any(grow)) {
#pragma unroll
      for (int m = 0; m < 2; m++)
#pragma unroll
        for (int r = 0; r < 4; r++) {
          float mt = mloc[m][r];
#pragma unroll
          for (int off = 1; off < 16; off <<= 1) mt = fmaxf(mt, __shfl_xor(mt, off));
          const float mnew = fmaxf(m_run[m][r], mt);
          const float sc = exp2f(m_run[m][r] - mnew);
          m_run[m][r] = mnew;
          lpart[m][r] *= sc;
          ctx[m][0][r] *= sc; ctx[m][1][r] *= sc; ctx[m][2][r] *= sc; ctx[m][3][r] *= sc;
        }
    }
    // exp2 + partial sums + pack P into wave-private LDS
#pragma unroll
    for (int m = 0; m < 2; m++)
#pragma unroll
      for (int r = 0; r < 4; r++) {
#pragma unroll
        for (int n = 0; n < 4; n++) {
          float p = exp2f(s[m][n][r] - m_run[m][r]);
          lpart[m][r] += p;
          *(short*)swz_addr(PlW, m * 16 + g * 4 + r, (n * 16 + c) * 2) = f2s(p);
        }
      }
    // PV from LDS
#pragma unroll
    for (int ks = 0; ks < 2; ks++) {
      short8 vfr[4];
#pragma unroll
      for (int d = 0; d < 4; d++)
        vfr[d] = *(const short8*)swz_addr(Vl[cur], d * 16 + c, ks * 64 + g * 16);
#pragma unroll
      for (int m = 0; m < 2; m++) {
        short8 pa = *(const short8*)swz_addr(PlW, m * 16 + c, ks * 64 + g * 16);
#pragma unroll
        for (int d = 0; d < 4; d++)
          ctx[m][d] = __builtin_amdgcn_mfma_f32_16x16x32_bf16(pa, vfr[d], ctx[m][d], 0, 0, 0);
      }
    }
    __syncthreads();   // drains vmcnt (staged tile ready) + LDS reads done
  }
#undef STAGE

  // epilogue
#pragma unroll
  for (int m = 0; m < 2; m++)
#pragma unroll
    for (int r = 0; r < 4; r++) {
      float l = lpart[m][r];
#pragma unroll
      for (int off = 1; off < 16; off <<= 1) l += __shfl_xor(l, off);
      const int rg = ((b * 16 + h) << 11) + qbase + m * 16 + g * 4 + r;
      const size_t base = ((size_t)half << 22) + (size_t)rg * 64;
#pragma unroll
      for (int d = 0; d < 4; d++)
        pctx[base + d * 16 + c] = f2s(ctx[m][d][r]);
      if (c == 0) ml[half * 65536 + rg] = make_float2(m_run[m][r], l);
    }
}

// ---------------- combine two KV-halves -> ctx bf16 [B*SQ][DIM] ----------------
__global__ __launch_bounds__(256) void combine_kernel(
    const short* __restrict__ pctx, const float2* __restrict__ ml,
    short* __restrict__ ctxb)
{
  const int t = blockIdx.x * 256 + threadIdx.x;   // 262144
  const int r = t >> 2;
  const int seg = (t & 3) * 16;
  const float2 ml0 = ml[r];
  const float2 ml1 = ml[65536 + r];
  const float m = fmaxf(ml0.x, ml1.x);
  const float w0 = exp2f(ml0.x - m);
  const float w1 = exp2f(ml1.x - m);
  const float inv = 1.0f / (ml0.y * w0 + ml1.y * w1);
  const short8 a0 = *(const short8*)&pctx[(size_t)r * 64 + seg];
  const short8 a1 = *(const short8*)&pctx[(size_t)r * 64 + seg + 8];
  const short8 b0 = *(const short8*)&pctx[(1ull << 22) + (size_t)r * 64 + seg];
  const short8 b1 = *(const short8*)&pctx[(1ull << 22) + (size_t)r * 64 + seg + 8];
  short8 o0, o1;
#pragma unroll
  for (int j = 0; j < 8; j++) {
    o0[j] = f2s((s2f(a0[j]) * w0 + s2f(b0[j]) * w1) * inv);
    o1[j] = f2s((s2f(a1[j]) * w0 + s2f(b1[j]) * w1) * inv);
  }
  const int b = r >> 15;
  const int h = (r >> 11) & 15;
  const int q = r & 2047;
  short* D = ctxb + (size_t)(b * 2048 + q) * 1024 + h * 64 + seg;
  *(short8*)&D[0] = o0;
  *(short8*)&D[8] = o1;
}

extern "C" void kernel_launch(void* const* d_in, const int* in_sizes, int n_in,
                              void* d_out, int out_size, void* d_ws, size_t ws_size,
                              hipStream_t stream)
{
  const float* x   = (const float*)d_in[0];
  const float* kc  = (const float*)d_in[1];
  const float* vc  = (const float*)d_in[2];
  const float* msk = (const float*)d_in[3];
  const float* Wq  = (const float*)d_in[4];
  const float* bq  = (const float*)d_in[5];
  const float* Wk  = (const float*)d_in[6];
  const float* bk  = (const float*)d_in[7];
  const float* Wv  = (const float*)d_in[8];
  const float* bv  = (const float*)d_in[9];
  const float* Wo  = (const float*)d_in[10];
  const float* bo  = (const float*)d_in[11];

  float* outf = (float*)d_out;
  float* kout = outf + 4194304;
  float* vout = outf + 12582912;

  short* ws_s  = (short*)d_ws;
  short* WT    = ws_s;                            // 8 MB
  short* xbf   = ws_s + (size_t)4 * 1048576;      // 8 MB (reused as ctx)
  short* qbf   = ws_s + (size_t)8 * 1048576;      // 8 MB
  short* Kbf   = ws_s + (size_t)12 * 1048576;     // 16 MB
  short* VTb   = ws_s + (size_t)20 * 1048576;     // 16 MB
  unsigned long long* maskW = (unsigned long long*)(ws_s + (size_t)28 * 1048576);  // 2 MB
  short* pctx  = ws_s + (size_t)44 * 1048576;     // 16 MB
  float2* mlp  = (float2*)(ws_s + (size_t)52 * 1048576);  // 1 MB
  short* ctxb  = xbf;

  const float qscale = 0.125f * LOG2E;

  convert_x_kernel<<<2048, 256, 0, stream>>>(x, xbf);
  transpose_w_kernel<<<1024, 256, 0, stream>>>(Wq, Wk, Wv, Wo, WT);
  copy_cache_kernel<<<4096, 256, 0, stream>>>(kc, vc, outf, Kbf);
  pack_mask_kernel<<<4096, 256, 0, stream>>>(msk, maskW);
  gemm_bt_bias<<<256, 256, 0, stream>>>(xbf, WT,               bq, nullptr, qbf, 2048, 0, qscale);
  gemm_bt_bias<<<256, 256, 0, stream>>>(xbf, WT + 1048576,     bk, kout, Kbf,   4096, 2048, 1.0f);
  gemm_bt_bias<<<256, 256, 0, stream>>>(xbf, WT + 2 * 1048576, bv, vout, nullptr, 4096, 2048, 1.0f);
  transpose_v_kernel<<<2048, 256, 0, stream>>>(vout, VTb);
  attn_kernel<<<1024, 256, 0, stream>>>(qbf, Kbf, VTb, maskW, pctx, mlp);
  combine_kernel<<<1024, 256, 0, stream>>>(pctx, mlp, ctxb);
  gemm_bt_bias<<<256, 256, 0, stream>>>(ctxb, WT + 3 * 1048576, bo, outf, nullptr, 2048, 0, 1.0f);
}